// Round 9
// baseline (467.218 us; speedup 1.0000x reference)
//
#include <hip/hip_runtime.h>
#include <hip/hip_bf16.h>
#include <cstdint>

#define TPB 256

constexpr int B = 8, C = 684, H = 64, W = 256;
constexpr int HID = 256, A = 512, K = 11;
constexpr int HW = H * W;      // 16384
constexpr int KK = K * K;      // 121
constexpr int KP = 128;        // padded tap count (K-dim for MFMA)

typedef __attribute__((ext_vector_type(8))) short bf16x8;
typedef __attribute__((ext_vector_type(4))) float f32x4;

__device__ __forceinline__ float fast_tanh(float x) {
    // tanh(x) = 1 - 2/(e^{2x}+1); saturates correctly at +/-inf
    float e = __expf(2.f * x);
    return 1.f - 2.f * __builtin_amdgcn_rcpf(e + 1.f);
}

__device__ __forceinline__ unsigned short f2bf(float f) {
    unsigned u = __float_as_uint(f);
    u += 0x7fffu + ((u >> 16) & 1u);   // RNE
    return (unsigned short)(u >> 16);
}

// Fused: query (blocks 0..15), fw (blocks 16..271), flag/cnt zeroing (block 0)
__global__ void prep_kernel(const float* __restrict__ hidden,
                            const float* __restrict__ W_h,
                            const float* __restrict__ b_h,
                            const float* __restrict__ conv_w,
                            const float* __restrict__ W_att,
                            float* __restrict__ query,
                            unsigned short* __restrict__ fwb,
                            int* __restrict__ cnt,
                            int* __restrict__ flag) {
    const int bx = blockIdx.x;
    if (bx == 0) {
        if (threadIdx.x < B) cnt[threadIdx.x] = 0;
        flag[threadIdx.x] = 0;            // B*H = 512 flags
        flag[256 + threadIdx.x] = 0;
    }
    if (bx < 16) {
        // query: hidden[b,k] wave-uniform (s_load); W_h row reads coalesced
        int b = bx >> 1;
        int a = ((bx & 1) << 8) + threadIdx.x;
        float q = b_h[a];
        const float* hb = hidden + b * HID;
        for (int k = 0; k < HID; ++k)
            q = fmaf(hb[k], W_h[k * A + a], q);
        query[b * A + a] = q;
    } else {
        int idx = (bx - 16) * TPB + threadIdx.x;   // A*KP = 65536
        int t = idx >> 9, a = idx & (A - 1);       // t uniform per half-block
        float v = 0.f;
        if (t < KK) {
            for (int ch = 0; ch < 512; ++ch)
                v = fmaf(conv_w[ch * KK + t], W_att[ch * A + a], v);
        }
        fwb[a * KP + t] = f2bf(v);
    }
}

// Implicit-GEMM energy kernel, a-split across 2 blocks; 2-deep trans prefetch;
// finalize fused via two-arrivals atomic (second block combines + softmax row partial).
// Block = (h, az, b): 256 pixels x 256 a. 8 waves, wave owns 32 a.
// MFMA 16x16x32 bf16: A = fw (a x taps), B = im2col patch (taps x pixels).
// C layout (m89-verified): col = lane&15 = pixel, row = (lane>>4)*4+reg = a-offset.
// NOTE: 2nd launch_bounds arg behaves as blocks/CU on this toolchain
// (measured r5: (512,4) -> 64-VGPR clamp -> spill disaster). (512,2) = 128 cap.
__global__ __launch_bounds__(512, 2) void energy_kernel(
    const float* __restrict__ alpha_sum,
    const float* __restrict__ trans,
    const float* __restrict__ query,
    const unsigned short* __restrict__ fwb,
    const float* __restrict__ W_alpha,
    const float* __restrict__ b_alpha,
    const float* __restrict__ mask,
    float* __restrict__ epart,
    float* __restrict__ energy,
    float* __restrict__ pm,
    float* __restrict__ ps,
    int* __restrict__ flag) {
    const int h = blockIdx.x, az = blockIdx.y, b = blockIdx.z;
    const int tid = threadIdx.x;
    const int lane = tid & 63, wid = tid >> 6;
    const int lg = lane >> 4, lr = lane & 15;   // k-group, row-in-16
    const int aw = az * 256 + wid * 32;         // wave's a-base

    __shared__ float nb[K][272];                   // 11.7 KB alpha_sum halo
    __shared__ unsigned short patch8[8 * 16 * KP]; // 32 KB: 8 pass-slices
    __shared__ float partAll[8][256];              // 8 KB per-wave partials
    __shared__ float erow[256];
    __shared__ float pmw[4], psw[4];
    __shared__ int sflag;

    // stage halo: rows h-5..h+5, cols -5..260
    const float* as_b = alpha_sum + b * HW;
    for (int idx = tid; idx < K * 266; idx += 512) {
        int r = idx / 266, j = idx - r * 266;
        int gh = h + r - 5, gw = j - 5;
        float v = 0.f;
        if (gh >= 0 && gh < H && gw >= 0 && gw < W) v = as_b[gh * W + gw];
        nb[r][j] = v;
    }

    // persistent fw A-frags: fw[aw+s*16+lr][ks*32 + lg*8 .. +7]
    bf16x8 fwf[2][4];
#pragma unroll
    for (int s = 0; s < 2; ++s)
#pragma unroll
        for (int ks = 0; ks < 4; ++ks)
            fwf[s][ks] = *(const bf16x8*)(fwb + (aw + s * 16 + lr) * KP + ks * 32 + lg * 8);

    // persistent per-lane query / W_alpha (match C-frag rows)
    float4 qv[2], wv[2];
#pragma unroll
    for (int s = 0; s < 2; ++s) {
        qv[s] = ((const float4*)(query + b * A + aw))[s * 4 + lg];
        wv[s] = ((const float4*)(W_alpha + aw))[s * 4 + lg];
    }

    // per-thread build assignment: pixel p, taps tap..tap+3
    const int bp = tid >> 5;              // pixel 0..15
    const int btap = (tid & 31) * 4;      // tap base, multiple of 4
    int boff[4];                          // nb flat offset, -1 if pad
#pragma unroll
    for (int j = 0; j < 4; ++j) {
        int t = btap + j;
        int r = t / K, c = t - r * K;
        boff[j] = (t < KK) ? (r * 272 + bp + c) : -1;
    }
    const int bdst = ((bp * KP + btap) ^ ((bp & 7) << 3));  // swizzled, ushort units

    const float* tb = trans + (size_t)b * A * HW + h * W;
    const float* nbf = &nb[0][0];

    // 2-deep trans prefetch, parity-named buffers (static indexing)
    float tA[2][4], tB[2][4];
#pragma unroll
    for (int s = 0; s < 2; ++s)
#pragma unroll
        for (int j = 0; j < 4; ++j) {
            const size_t rowoff = (size_t)(aw + s * 16 + lg * 4 + j) * HW + lr;
            tA[s][j] = tb[rowoff];          // pass 0
            tB[s][j] = tb[rowoff + 16];     // pass 1
        }
    __syncthreads();

#pragma unroll
    for (int half = 0; half < 2; ++half) {
        // ---- build patch for passes half*8 .. half*8+7 ----
#pragma unroll
        for (int pp = 0; pp < 8; ++pp) {
            const int p0 = (half * 8 + pp) * 16;
            unsigned short e[4];
#pragma unroll
            for (int j = 0; j < 4; ++j)
                e[j] = (boff[j] >= 0) ? f2bf(nbf[boff[j] + p0]) : (unsigned short)0;
            uint2 pk;
            pk.x = (unsigned)e[0] | ((unsigned)e[1] << 16);
            pk.y = (unsigned)e[2] | ((unsigned)e[3] << 16);
            *(uint2*)&patch8[pp * 2048 + bdst] = pk;
        }
        __syncthreads();   // patch slab ready

        // ---- 8 fully-unrolled passes (no barriers) ----
#pragma unroll
        for (int pp = 0; pp < 8; ++pp) {
            const int pass = half * 8 + pp;
            const int p0 = pass * 16;

            f32x4 acc[2];
#pragma unroll
            for (int s = 0; s < 2; ++s) acc[s] = (f32x4){0.f, 0.f, 0.f, 0.f};
#pragma unroll
            for (int ks = 0; ks < 4; ++ks) {
                int idx = pp * 2048 + ((lr * KP + ks * 32 + lg * 8) ^ ((lr & 7) << 3));
                bf16x8 pf = *(const bf16x8*)&patch8[idx];
#pragma unroll
                for (int s = 0; s < 2; ++s)
                    acc[s] = __builtin_amdgcn_mfma_f32_16x16x32_bf16(fwf[s][ks], pf, acc[s], 0, 0, 0);
            }

            // epilogue consumes this pass's buffer (parity-static)
            float es = 0.f;
#pragma unroll
            for (int s = 0; s < 2; ++s) {
#pragma unroll
                for (int j = 0; j < 4; ++j) {
                    float tj = (pass & 1) ? tB[s][j] : tA[s][j];
                    float qj = (j == 0) ? qv[s].x : (j == 1) ? qv[s].y : (j == 2) ? qv[s].z : qv[s].w;
                    float wj = (j == 0) ? wv[s].x : (j == 1) ? wv[s].y : (j == 2) ? wv[s].z : wv[s].w;
                    float x = acc[s][j] + tj + qj;
                    es = fmaf(fast_tanh(x), wj, es);
                }
            }
            es += __shfl_xor(es, 16, 64);
            es += __shfl_xor(es, 32, 64);
            if (lane < 16) partAll[wid][p0 + lane] = es;   // own slice, no barrier

            // refill the just-consumed buffer with pass+2 (2-pass window)
            if (pass + 2 < 16) {
                const int pf2 = (pass + 2) * 16;
#pragma unroll
                for (int s = 0; s < 2; ++s)
#pragma unroll
                    for (int j = 0; j < 4; ++j) {
                        const size_t rowoff = (size_t)(aw + s * 16 + lg * 4 + j) * HW + pf2 + lr;
                        if (pass & 1) tB[s][j] = tb[rowoff];
                        else          tA[s][j] = tb[rowoff];
                    }
            }
        }
        __syncthreads();   // all reads of patch slab done (and partials visible)
    }

    // ---- own-half reduce -> epart + erow ----
    if (tid < 256) {
        float e = 0.f;
#pragma unroll
        for (int wv2 = 0; wv2 < 8; ++wv2) e += partAll[wv2][tid];
        erow[tid] = e;
        epart[(((size_t)b * H + h) * 2 + az) * 256 + tid] = e;
    }
    __threadfence();       // release own epart half (device scope)
    __syncthreads();
    if (tid == 0) sflag = atomicAdd(&flag[b * H + h], 1);
    __syncthreads();
    if (sflag != 1) return;   // first arrival: done

    // ---- second arrival: combine halves + energy + per-row softmax partial ----
    __threadfence();          // acquire other half's writes
    if (tid < 256) {
        const size_t obase = (((size_t)b * H + h) * 2 + (1 - az)) * 256;
        float e = (erow[tid] + epart[obase + tid]) + b_alpha[0];
        energy[(b * H + h) * W + tid] = e;

        float s = mask[b * HW + h * W + tid];   // exp(e-e)*mk
        float m = e;
#pragma unroll
        for (int off = 1; off < 64; off <<= 1) {
            float m2 = __shfl_xor(m, off, 64);
            float s2 = __shfl_xor(s, off, 64);
            float nm = fmaxf(m, m2);
            s = s * __expf(m - nm) + s2 * __expf(m2 - nm);
            m = nm;
        }
        if ((tid & 63) == 0) { pmw[tid >> 6] = m; psw[tid >> 6] = s; }
    }
    __syncthreads();
    if (tid == 0) {
        float m = pmw[0], s = psw[0];
#pragma unroll
        for (int i = 1; i < 4; ++i) {
            float m2 = pmw[i], s2 = psw[i];
            float nm = fmaxf(m, m2);
            s = s * __expf(m - nm) + s2 * __expf(m2 - nm);
            m = nm;
        }
        pm[b * H + h] = m;
        ps[b * H + h] = s;
    }
}

// alpha + new_alpha_sum + sparse gather of (alpha > 0.02) pixels.
__global__ void alpha_kernel(const float* __restrict__ energy,
                             const float* __restrict__ mask,
                             const float* __restrict__ alpha_sum,
                             const float* __restrict__ pm,
                             const float* __restrict__ ps,
                             float* __restrict__ out_alpha,
                             float* __restrict__ out_nas,
                             int* __restrict__ cnt,
                             int* __restrict__ gidx,
                             float* __restrict__ gval) {
    const int i4 = blockIdx.x * TPB + threadIdx.x;   // float4 index, B*HW/4 total
    const int b = i4 >> 12;                          // uniform per block
    __shared__ float smax, sinv;
    if (threadIdx.x < 64) {
        float m = pm[b * H + threadIdx.x];
        float s = ps[b * H + threadIdx.x];
#pragma unroll
        for (int off = 32; off > 0; off >>= 1) {
            float m2 = __shfl_xor(m, off, 64);
            float s2 = __shfl_xor(s, off, 64);
            float nm = fmaxf(m, m2);
            s = s * __expf(m - nm) + s2 * __expf(m2 - nm);
            m = nm;
        }
        if (threadIdx.x == 0) { smax = m; sinv = 1.f / (s + 1e-10f); }
    }
    __syncthreads();
    const float mx = smax, iv = sinv;

    float4 ev = ((const float4*)energy)[i4];
    float4 mv = ((const float4*)mask)[i4];
    float4 asv = ((const float4*)alpha_sum)[i4];
    float4 al;
    al.x = __expf(ev.x - mx) * mv.x * iv;
    al.y = __expf(ev.y - mx) * mv.y * iv;
    al.z = __expf(ev.z - mx) * mv.z * iv;
    al.w = __expf(ev.w - mx) * mv.w * iv;
    ((float4*)out_alpha)[i4] = al;
    float4 nv;
    nv.x = al.x + asv.x; nv.y = al.y + asv.y;
    nv.z = al.z + asv.z; nv.w = al.w + asv.w;
    ((float4*)out_nas)[i4] = nv;

    // sparse gather (expected: ~0 passing pixels for softmax over 16K)
    const int p0 = (i4 << 2) & (HW - 1);
#pragma unroll
    for (int j = 0; j < 4; ++j) {
        float a = (j == 0) ? al.x : (j == 1) ? al.y : (j == 2) ? al.z : al.w;
        if (a > 0.02f) {
            int slot = atomicAdd(&cnt[b], 1);
            gidx[b * HW + slot] = p0 + j;
            gval[b * HW + slot] = a;
        }
    }
}

// context[b,c] = sum over gathered pixels: gval * feat[b,c,gidx]
__global__ void context_kernel(const float* __restrict__ feat,
                               const int* __restrict__ cnt,
                               const int* __restrict__ gidx,
                               const float* __restrict__ gval,
                               float* __restrict__ out_ctx) {
    const int c = blockIdx.x, b = blockIdx.y;
    const int n = cnt[b];
    const float* fb = feat + ((size_t)b * C + c) * HW;
    float s = 0.f;
    for (int k = threadIdx.x; k < n; k += 64)
        s += gval[b * HW + k] * fb[gidx[b * HW + k]];
#pragma unroll
    for (int off = 32; off > 0; off >>= 1) s += __shfl_down(s, off, 64);
    if (threadIdx.x == 0) out_ctx[b * C + c] = s;
}

extern "C" void kernel_launch(void* const* d_in, const int* in_sizes, int n_in,
                              void* d_out, int out_size, void* d_ws, size_t ws_size,
                              hipStream_t stream) {
    const float* cnn_features = (const float*)d_in[0];
    const float* trans        = (const float*)d_in[1];
    const float* hidden       = (const float*)d_in[2];
    const float* alpha_sum    = (const float*)d_in[3];
    const float* image_mask   = (const float*)d_in[4];
    const float* W_h          = (const float*)d_in[5];
    const float* b_h          = (const float*)d_in[6];
    const float* conv_w       = (const float*)d_in[7];
    const float* W_att        = (const float*)d_in[8];
    const float* W_alpha      = (const float*)d_in[9];
    const float* b_alpha      = (const float*)d_in[10];

    float* out       = (float*)d_out;
    float* out_ctx   = out;               // B*C
    float* out_alpha = out + B * C;       // B*HW
    float* out_nas   = out_alpha + B * HW;

    float* ws = (float*)d_ws;
    float*          query  = ws;                           // 4096 f
    unsigned short* fwb    = (unsigned short*)(ws + 4096); // 65536 ushort
    float*          energy = ws + 4096 + 32768;            // 131072 f
    float*          pm     = energy + B * HW;              // 512
    float*          ps     = pm + B * H;                   // 512
    int*            cnt    = (int*)(ps + B * H);           // 8
    int*            flag   = cnt + 8;                      // 512
    int*            gidx   = flag + 512;                   // B*HW
    float*          gval   = (float*)(gidx + B * HW);      // B*HW
    float*          epart  = gval + B * HW;                // B*H*2*256

    hipLaunchKernelGGL(prep_kernel, dim3(16 + (A * KP) / TPB), dim3(TPB), 0, stream,
                       hidden, W_h, b_h, conv_w, W_att, query, fwb, cnt, flag);
    hipLaunchKernelGGL(energy_kernel, dim3(H, 2, B), dim3(512), 0, stream,
                       alpha_sum, trans, query, fwb, W_alpha, b_alpha, image_mask,
                       epart, energy, pm, ps, flag);
    hipLaunchKernelGGL(alpha_kernel, dim3(B * HW / (TPB * 4)), dim3(TPB), 0, stream,
                       energy, image_mask, alpha_sum, pm, ps,
                       out_alpha, out_nas, cnt, gidx, gval);
    hipLaunchKernelGGL(context_kernel, dim3(C, B), dim3(64), 0, stream,
                       cnn_features, cnt, gidx, gval, out_ctx);
}

// Round 10
// 101.461 us; speedup vs baseline: 4.6049x; 4.6049x over previous
//
#include <hip/hip_runtime.h>
#include <hip/hip_bf16.h>
#include <cstdint>

#define TPB 256

constexpr int B = 8, C = 684, H = 64, W = 256;
constexpr int HID = 256, A = 512, K = 11;
constexpr int HW = H * W;      // 16384
constexpr int KK = K * K;      // 121
constexpr int KP = 128;        // padded tap count (K-dim for MFMA)

typedef __attribute__((ext_vector_type(8))) short bf16x8;
typedef __attribute__((ext_vector_type(4))) float f32x4;

__device__ __forceinline__ float fast_tanh(float x) {
    // tanh(x) = 1 - 2/(e^{2x}+1); saturates correctly at +/-inf
    float e = __expf(2.f * x);
    return 1.f - 2.f * __builtin_amdgcn_rcpf(e + 1.f);
}

__device__ __forceinline__ unsigned short f2bf(float f) {
    unsigned u = __float_as_uint(f);
    u += 0x7fffu + ((u >> 16) & 1u);   // RNE
    return (unsigned short)(u >> 16);
}

// Fused: query (blocks 0..15), fw (blocks 16..271), cnt zeroing (block 0)
__global__ void prep_kernel(const float* __restrict__ hidden,
                            const float* __restrict__ W_h,
                            const float* __restrict__ b_h,
                            const float* __restrict__ conv_w,
                            const float* __restrict__ W_att,
                            float* __restrict__ query,
                            unsigned short* __restrict__ fwb,
                            int* __restrict__ cnt) {
    const int bx = blockIdx.x;
    if (bx == 0 && threadIdx.x < B) cnt[threadIdx.x] = 0;   // reset gather counters
    if (bx < 16) {
        // query: hidden[b,k] wave-uniform (s_load); W_h row reads coalesced
        int b = bx >> 1;
        int a = ((bx & 1) << 8) + threadIdx.x;
        float q = b_h[a];
        const float* hb = hidden + b * HID;
        for (int k = 0; k < HID; ++k)
            q = fmaf(hb[k], W_h[k * A + a], q);
        query[b * A + a] = q;
    } else {
        int idx = (bx - 16) * TPB + threadIdx.x;   // A*KP = 65536
        int t = idx >> 9, a = idx & (A - 1);       // t uniform per half-block
        float v = 0.f;
        if (t < KK) {
            for (int ch = 0; ch < 512; ++ch)
                v = fmaf(conv_w[ch * KK + t], W_att[ch * A + a], v);
        }
        fwb[a * KP + t] = f2bf(v);
    }
}

// Implicit-GEMM energy kernel, a-split across 4 blocks of 256 threads.
// Block = (h, az, b): 256 pixels x 128 a. 4 waves, wave owns 32 a.
// MFMA 16x16x32 bf16: A = fw (a x taps), B = im2col patch (taps x pixels).
// C layout (m89-verified): col = lane&15 = pixel, row = (lane>>4)*4+reg = a-offset.
// VGPR empirics on this toolchain: 512-thread blocks clamp to 64 VGPR
// ((512,2) r9 and (512,4) r5 both measured 64 -> spills); 256-thread blocks
// get larger budgets (r2: 76 used). (256,4) = 128 cap under BOTH readings of
// the 2nd arg (waves/EU or blocks/CU). Live set ~85 -> no spill.
__global__ __launch_bounds__(256, 4) void energy_kernel(
    const float* __restrict__ alpha_sum,
    const float* __restrict__ trans,
    const float* __restrict__ query,
    const unsigned short* __restrict__ fwb,
    const float* __restrict__ W_alpha,
    float* __restrict__ epart) {
    const int h = blockIdx.x, az = blockIdx.y, b = blockIdx.z;
    const int tid = threadIdx.x;
    const int lane = tid & 63, wid = tid >> 6;  // wid 0..3
    const int lg = lane >> 4, lr = lane & 15;   // k-group, row-in-16
    const int aw = az * 128 + wid * 32;         // wave's a-base

    __shared__ float nb[K][272];                   // 11.7 KB alpha_sum halo
    __shared__ unsigned short patch8[8 * 16 * KP]; // 32 KB: 8 pass-slices
    __shared__ float partAll[4][256];              // 4 KB per-wave partials

    // stage halo: rows h-5..h+5, cols -5..260
    const float* as_b = alpha_sum + b * HW;
    for (int idx = tid; idx < K * 266; idx += 256) {
        int r = idx / 266, j = idx - r * 266;
        int gh = h + r - 5, gw = j - 5;
        float v = 0.f;
        if (gh >= 0 && gh < H && gw >= 0 && gw < W) v = as_b[gh * W + gw];
        nb[r][j] = v;
    }

    // persistent fw A-frags: fw[aw+s*16+lr][ks*32 + lg*8 .. +7]
    bf16x8 fwf[2][4];
#pragma unroll
    for (int s = 0; s < 2; ++s)
#pragma unroll
        for (int ks = 0; ks < 4; ++ks)
            fwf[s][ks] = *(const bf16x8*)(fwb + (aw + s * 16 + lr) * KP + ks * 32 + lg * 8);

    // per-thread build assignment: pixels bp and bp+8, taps btap..btap+3
    const int bp = tid >> 5;              // 0..7
    const int btap = (tid & 31) * 4;      // tap base, multiple of 4
    int boff[4];                          // nb flat offset for pixel bp, -1 if pad
#pragma unroll
    for (int j = 0; j < 4; ++j) {
        int t = btap + j;
        int r = t / K, c = t - r * K;
        boff[j] = (t < KK) ? (r * 272 + bp + c) : -1;
    }
    // (bp+8)&7 == bp&7 -> same XOR term; dst just shifts by 8 rows
    const int bdst = ((bp * KP + btap) ^ ((bp & 7) << 3));  // ushort units
    const int bdst2 = bdst + 8 * KP;

    const float4* q4 = (const float4*)(query + b * A + aw);   // L1-resident
    const float4* w4 = (const float4*)(W_alpha + aw);         // L1-resident
    const float* tb = trans + (size_t)b * A * HW + h * W;
    const float* nbf = &nb[0][0];
    __syncthreads();

    // prologue: trans for pass 0
    float tc[2][4];
#pragma unroll
    for (int s = 0; s < 2; ++s)
#pragma unroll
        for (int j = 0; j < 4; ++j)
            tc[s][j] = tb[(size_t)(aw + s * 16 + lg * 4 + j) * HW + lr];

    for (int half = 0; half < 2; ++half) {
        // ---- build patch for passes half*8 .. half*8+7 (2 pixels/thread) ----
#pragma unroll
        for (int pp = 0; pp < 8; ++pp) {
            const int p0 = (half * 8 + pp) * 16;
            unsigned short e[4], e2[4];
#pragma unroll
            for (int j = 0; j < 4; ++j) {
                e[j]  = (boff[j] >= 0) ? f2bf(nbf[boff[j] + p0])     : (unsigned short)0;
                e2[j] = (boff[j] >= 0) ? f2bf(nbf[boff[j] + p0 + 8]) : (unsigned short)0;
            }
            uint2 pk, pk2;
            pk.x  = (unsigned)e[0]  | ((unsigned)e[1]  << 16);
            pk.y  = (unsigned)e[2]  | ((unsigned)e[3]  << 16);
            pk2.x = (unsigned)e2[0] | ((unsigned)e2[1] << 16);
            pk2.y = (unsigned)e2[2] | ((unsigned)e2[3] << 16);
            *(uint2*)&patch8[pp * 2048 + bdst]  = pk;
            *(uint2*)&patch8[pp * 2048 + bdst2] = pk2;
        }
        __syncthreads();   // patch slab ready

        // ---- 8 free-running passes (no barriers); tn prefetches pass+1 ----
        for (int pp = 0; pp < 8; ++pp) {
            const int pass = half * 8 + pp;
            const int p0 = pass * 16;
            const int p0n = (pass < 15 ? pass + 1 : pass) * 16;

            // prefetch next pass's trans (consumed next iteration)
            float tn[2][4];
#pragma unroll
            for (int s = 0; s < 2; ++s)
#pragma unroll
                for (int j = 0; j < 4; ++j)
                    tn[s][j] = tb[(size_t)(aw + s * 16 + lg * 4 + j) * HW + p0n + lr];

            f32x4 acc[2];
#pragma unroll
            for (int s = 0; s < 2; ++s) acc[s] = (f32x4){0.f, 0.f, 0.f, 0.f};
#pragma unroll
            for (int ks = 0; ks < 4; ++ks) {
                int idx = pp * 2048 + ((lr * KP + ks * 32 + lg * 8) ^ ((lr & 7) << 3));
                bf16x8 pf = *(const bf16x8*)&patch8[idx];
#pragma unroll
                for (int s = 0; s < 2; ++s)
                    acc[s] = __builtin_amdgcn_mfma_f32_16x16x32_bf16(fwf[s][ks], pf, acc[s], 0, 0, 0);
            }

            // epilogue: tanh(cov + q + trans) * w_alpha, reduce over a
            float es = 0.f;
#pragma unroll
            for (int s = 0; s < 2; ++s) {
                float4 qv = q4[s * 4 + lg];
                float4 wv = w4[s * 4 + lg];
#pragma unroll
                for (int j = 0; j < 4; ++j) {
                    float qj = (j == 0) ? qv.x : (j == 1) ? qv.y : (j == 2) ? qv.z : qv.w;
                    float wj = (j == 0) ? wv.x : (j == 1) ? wv.y : (j == 2) ? wv.z : wv.w;
                    float x = acc[s][j] + tc[s][j] + qj;
                    es = fmaf(fast_tanh(x), wj, es);
                }
            }
            // lanes {l, l^16, l^32, l^48} share pixel lr -> reduce over a-groups
            es += __shfl_xor(es, 16, 64);
            es += __shfl_xor(es, 32, 64);
            if (lane < 16) partAll[wid][p0 + lane] = es;   // own slice, no barrier

#pragma unroll
            for (int s = 0; s < 2; ++s)
#pragma unroll
                for (int j = 0; j < 4; ++j)
                    tc[s][j] = tn[s][j];
        }
        __syncthreads();   // all reads of patch slab done (and partials visible)
    }

    // ---- final: cross-wave reduce over this block's 128 a -> epart ----
    {
        float e = 0.f;
#pragma unroll
        for (int wv = 0; wv < 4; ++wv) e += partAll[wv][tid];
        epart[(((size_t)b * H + h) * 4 + az) * 256 + tid] = e;
    }
}

// finalize: energy = sum of 4 epart quarters + b_alpha; per-row softmax partials
__global__ void finalize_kernel(const float* __restrict__ epart,
                                const float* __restrict__ b_alpha,
                                const float* __restrict__ mask,
                                float* __restrict__ energy,
                                float* __restrict__ pm,
                                float* __restrict__ ps) {
    const int h = blockIdx.x, b = blockIdx.y;
    const int tid = threadIdx.x;
    const size_t base = ((size_t)b * H + h) * 1024;
    float e = epart[base + tid] + epart[base + 256 + tid] +
              epart[base + 512 + tid] + epart[base + 768 + tid] + b_alpha[0];
    energy[(b * H + h) * W + tid] = e;

    __shared__ float pmw[4], psw[4];
    float s = mask[b * HW + h * W + tid];   // exp(e-e)*mk
    float m = e;
#pragma unroll
    for (int off = 1; off < 64; off <<= 1) {
        float m2 = __shfl_xor(m, off, 64);
        float s2 = __shfl_xor(s, off, 64);
        float nm = fmaxf(m, m2);
        s = s * __expf(m - nm) + s2 * __expf(m2 - nm);
        m = nm;
    }
    if ((tid & 63) == 0) { pmw[tid >> 6] = m; psw[tid >> 6] = s; }
    __syncthreads();
    if (tid == 0) {
        float mm = pmw[0], ss = psw[0];
#pragma unroll
        for (int i = 1; i < 4; ++i) {
            float m2 = pmw[i], s2 = psw[i];
            float nm = fmaxf(mm, m2);
            ss = ss * __expf(mm - nm) + s2 * __expf(m2 - nm);
            mm = nm;
        }
        pm[b * H + h] = mm;
        ps[b * H + h] = ss;
    }
}

// alpha + new_alpha_sum + sparse gather of (alpha > 0.02) pixels.
__global__ void alpha_kernel(const float* __restrict__ energy,
                             const float* __restrict__ mask,
                             const float* __restrict__ alpha_sum,
                             const float* __restrict__ pm,
                             const float* __restrict__ ps,
                             float* __restrict__ out_alpha,
                             float* __restrict__ out_nas,
                             int* __restrict__ cnt,
                             int* __restrict__ gidx,
                             float* __restrict__ gval) {
    const int i4 = blockIdx.x * TPB + threadIdx.x;   // float4 index, B*HW/4 total
    const int b = i4 >> 12;                          // uniform per block
    __shared__ float smax, sinv;
    if (threadIdx.x < 64) {
        float m = pm[b * H + threadIdx.x];
        float s = ps[b * H + threadIdx.x];
#pragma unroll
        for (int off = 32; off > 0; off >>= 1) {
            float m2 = __shfl_xor(m, off, 64);
            float s2 = __shfl_xor(s, off, 64);
            float nm = fmaxf(m, m2);
            s = s * __expf(m - nm) + s2 * __expf(m2 - nm);
            m = nm;
        }
        if (threadIdx.x == 0) { smax = m; sinv = 1.f / (s + 1e-10f); }
    }
    __syncthreads();
    const float mx = smax, iv = sinv;

    float4 ev = ((const float4*)energy)[i4];
    float4 mv = ((const float4*)mask)[i4];
    float4 asv = ((const float4*)alpha_sum)[i4];
    float4 al;
    al.x = __expf(ev.x - mx) * mv.x * iv;
    al.y = __expf(ev.y - mx) * mv.y * iv;
    al.z = __expf(ev.z - mx) * mv.z * iv;
    al.w = __expf(ev.w - mx) * mv.w * iv;
    ((float4*)out_alpha)[i4] = al;
    float4 nv;
    nv.x = al.x + asv.x; nv.y = al.y + asv.y;
    nv.z = al.z + asv.z; nv.w = al.w + asv.w;
    ((float4*)out_nas)[i4] = nv;

    // sparse gather (expected: ~0 passing pixels for softmax over 16K)
    const int p0 = (i4 << 2) & (HW - 1);
#pragma unroll
    for (int j = 0; j < 4; ++j) {
        float a = (j == 0) ? al.x : (j == 1) ? al.y : (j == 2) ? al.z : al.w;
        if (a > 0.02f) {
            int slot = atomicAdd(&cnt[b], 1);
            gidx[b * HW + slot] = p0 + j;
            gval[b * HW + slot] = a;
        }
    }
}

// context[b,c] = sum over gathered pixels: gval * feat[b,c,gidx]
__global__ void context_kernel(const float* __restrict__ feat,
                               const int* __restrict__ cnt,
                               const int* __restrict__ gidx,
                               const float* __restrict__ gval,
                               float* __restrict__ out_ctx) {
    const int c = blockIdx.x, b = blockIdx.y;
    const int n = cnt[b];
    const float* fb = feat + ((size_t)b * C + c) * HW;
    float s = 0.f;
    for (int k = threadIdx.x; k < n; k += 64)
        s += gval[b * HW + k] * fb[gidx[b * HW + k]];
#pragma unroll
    for (int off = 32; off > 0; off >>= 1) s += __shfl_down(s, off, 64);
    if (threadIdx.x == 0) out_ctx[b * C + c] = s;
}

extern "C" void kernel_launch(void* const* d_in, const int* in_sizes, int n_in,
                              void* d_out, int out_size, void* d_ws, size_t ws_size,
                              hipStream_t stream) {
    const float* cnn_features = (const float*)d_in[0];
    const float* trans        = (const float*)d_in[1];
    const float* hidden       = (const float*)d_in[2];
    const float* alpha_sum    = (const float*)d_in[3];
    const float* image_mask   = (const float*)d_in[4];
    const float* W_h          = (const float*)d_in[5];
    const float* b_h          = (const float*)d_in[6];
    const float* conv_w       = (const float*)d_in[7];
    const float* W_att        = (const float*)d_in[8];
    const float* W_alpha      = (const float*)d_in[9];
    const float* b_alpha      = (const float*)d_in[10];

    float* out       = (float*)d_out;
    float* out_ctx   = out;               // B*C
    float* out_alpha = out + B * C;       // B*HW
    float* out_nas   = out_alpha + B * HW;

    float* ws = (float*)d_ws;
    float*          query  = ws;                           // 4096 f
    unsigned short* fwb    = (unsigned short*)(ws + 4096); // 65536 ushort
    float*          energy = ws + 4096 + 32768;            // 131072 f
    float*          pm     = energy + B * HW;              // 512
    float*          ps     = pm + B * H;                   // 512
    int*            cnt    = (int*)(ps + B * H);           // 8
    int*            gidx   = cnt + 8;                      // B*HW
    float*          gval   = (float*)(gidx + B * HW);      // B*HW
    float*          epart  = gval + B * HW;                // B*H*4*256 = 524288 f

    hipLaunchKernelGGL(prep_kernel, dim3(16 + (A * KP) / TPB), dim3(TPB), 0, stream,
                       hidden, W_h, b_h, conv_w, W_att, query, fwb, cnt);
    hipLaunchKernelGGL(energy_kernel, dim3(H, 4, B), dim3(256), 0, stream,
                       alpha_sum, trans, query, fwb, W_alpha, epart);
    hipLaunchKernelGGL(finalize_kernel, dim3(H, B), dim3(TPB), 0, stream,
                       epart, b_alpha, image_mask, energy, pm, ps);
    hipLaunchKernelGGL(alpha_kernel, dim3(B * HW / (TPB * 4)), dim3(TPB), 0, stream,
                       energy, image_mask, alpha_sum, pm, ps,
                       out_alpha, out_nas, cnt, gidx, gval);
    hipLaunchKernelGGL(context_kernel, dim3(C, B), dim3(64), 0, stream,
                       cnn_features, cnt, gidx, gval, out_ctx);
}